// Round 1
// baseline (631.466 us; speedup 1.0000x reference)
//
#include <hip/hip_runtime.h>
#include <hip/hip_bf16.h>

// ---------- common helpers ----------
typedef __attribute__((ext_vector_type(8))) short short8;
typedef __attribute__((ext_vector_type(4))) float floatx4;

__device__ __forceinline__ ushort f2bf(float x) {
    unsigned u = __float_as_uint(x);
    unsigned r = (u + 0x7fffu + ((u >> 16) & 1u)) >> 16;
    return (ushort)r;
}
__device__ __forceinline__ float bf2f(ushort h) {
    return __uint_as_float(((unsigned)h) << 16);
}
__device__ __forceinline__ float fast_sigmoid(float x) {
    return 1.0f / (1.0f + __expf(-x));
}
__device__ __forceinline__ float fast_tanh(float x) {
    x = fminf(fmaxf(x, -15.0f), 15.0f);
    float e = __expf(2.0f * x);
    return (e - 1.0f) / (e + 1.0f);
}
__device__ __forceinline__ void load_lds16(const void* g, void* l) {
    __builtin_amdgcn_global_load_lds(
        (__attribute__((address_space(1))) void*)(g),
        (__attribute__((address_space(3))) void*)(l),
        16, 0, 0);
}

// ---------- fp32 -> bf16 conversion ----------
__global__ __launch_bounds__(256) void cvt_f32_bf16(const float* __restrict__ src,
                                                    ushort* __restrict__ dst, int n4) {
    int i = blockIdx.x * blockDim.x + threadIdx.x;
    if (i >= n4) return;
    const float4 v = ((const float4*)src)[i];
    ushort4 o;
    o.x = f2bf(v.x); o.y = f2bf(v.y); o.z = f2bf(v.z); o.w = f2bf(v.w);
    ((ushort4*)dst)[i] = o;
}

// ---------- GEMM: C[M,N] = A[M,K] * B[N,K]^T  (both bf16, fp32 accum) ----------
// MODE 0: plain, store bf16
// MODE 1: +bias, relu, store bf16
// MODE 2: +bias, relu, store bf16 AND fp32
template <int MODE>
__global__ __launch_bounds__(256) void gemm_bt(
    const ushort* __restrict__ A, int lda,
    const ushort* __restrict__ B, int ldb,
    const float* __restrict__ bias,
    ushort* __restrict__ Cb, float* __restrict__ Cf, int ldc,
    int K) {
    __shared__ __attribute__((aligned(16))) ushort sA[128 * 64];
    __shared__ __attribute__((aligned(16))) ushort sB[128 * 64];

    const int tid = threadIdx.x;
    const int lane = tid & 63;
    const int w = tid >> 6;          // wave 0..3
    const int m0 = blockIdx.y * 128;
    const int n0 = blockIdx.x * 128;
    const int wm = (w >> 1) * 64;    // wave's m offset within tile
    const int wn = (w & 1) * 64;     // wave's n offset within tile

    const int lrow = lane >> 3;        // 0..7
    const int lcol = (lane & 7) * 8;   // 0..56 step 8

    floatx4 acc[4][4] = {};

    for (int k0 = 0; k0 < K; k0 += 64) {
#pragma unroll
        for (int j = 0; j < 4; ++j) {
            int idx = w * 4 + j;  // 16 chunks of 512 elems (8 rows each)
            const ushort* ga = A + (size_t)(m0 + idx * 8 + lrow) * lda + k0 + lcol;
            load_lds16(ga, &sA[idx * 512]);
            const ushort* gb = B + (size_t)(n0 + idx * 8 + lrow) * ldb + k0 + lcol;
            load_lds16(gb, &sB[idx * 512]);
        }
        __syncthreads();  // drains vmcnt (global_load_lds) per HIP barrier semantics
#pragma unroll
        for (int kk = 0; kk < 2; ++kk) {
            const int col = kk * 32 + (lane >> 4) * 8;
            short8 a[4], b[4];
#pragma unroll
            for (int i = 0; i < 4; ++i) {
                a[i] = *(const short8*)&sA[(wm + i * 16 + (lane & 15)) * 64 + col];
                b[i] = *(const short8*)&sB[(wn + i * 16 + (lane & 15)) * 64 + col];
            }
#pragma unroll
            for (int i = 0; i < 4; ++i)
#pragma unroll
                for (int j = 0; j < 4; ++j)
                    acc[i][j] = __builtin_amdgcn_mfma_f32_16x16x32_bf16(a[i], b[j], acc[i][j], 0, 0, 0);
        }
        __syncthreads();
    }

    // epilogue: C/D layout row=(lane>>4)*4+reg, col=lane&15
    const int ml = (lane >> 4) * 4;
    const int nl = lane & 15;
#pragma unroll
    for (int j = 0; j < 4; ++j) {
        const int n = n0 + wn + j * 16 + nl;
        float bv = 0.0f;
        if (MODE > 0) bv = bias[n];
#pragma unroll
        for (int i = 0; i < 4; ++i) {
            const int mbase = m0 + wm + i * 16 + ml;
#pragma unroll
            for (int r = 0; r < 4; ++r) {
                float v = acc[i][j][r];
                if (MODE > 0) { v += bv; v = fmaxf(v, 0.0f); }
                size_t off = (size_t)(mbase + r) * ldc + n;
                Cb[off] = f2bf(v);
                if (MODE == 2) Cf[off] = v;
            }
        }
    }
}

// ---------- v_net: tanh(enc @ W_v^T + b_v), one wave per row ----------
__global__ __launch_bounds__(256) void v_kernel(const ushort* __restrict__ enc,
                                                const float* __restrict__ Wv,
                                                const float* __restrict__ bv,
                                                float* __restrict__ out) {
    const int row = blockIdx.x * 4 + (threadIdx.x >> 6);
    const int lane = threadIdx.x & 63;
    const ushort* e = enc + (size_t)row * 1024;
    float s = 0.0f;
#pragma unroll
    for (int i = 0; i < 16; ++i) {
        int k = lane + i * 64;
        s += bf2f(e[k]) * Wv[k];
    }
#pragma unroll
    for (int off = 32; off; off >>= 1) s += __shfl_down(s, off, 64);
    if (lane == 0) out[row] = fast_tanh(s + bv[0]);
}

// ---------- GRU gate fusion: h = (1-z)*n + z*h, masked by t < cnt[b] ----------
__global__ __launch_bounds__(256) void gate_kernel(
    const ushort* __restrict__ gi, const ushort* __restrict__ gh,
    const float* __restrict__ bih, const float* __restrict__ bhh,
    float* __restrict__ hf, ushort* __restrict__ hb,
    const int* __restrict__ cnt, int t) {
    const int b = blockIdx.x;
    if (t >= cnt[b]) return;  // padded slot: h unchanged (block-uniform branch)
    const int j = threadIdx.x * 2;
    const ushort* gib = gi + (size_t)b * 1536;
    const ushort* ghb = gh + (size_t)b * 1536;
    float* hfp = hf + (size_t)b * 512 + j;
    ushort* hbp = hb + (size_t)b * 512 + j;
#pragma unroll
    for (int u = 0; u < 2; ++u) {
        const int jj = j + u;
        float ir = bf2f(gib[jj]) + bih[jj];
        float iz = bf2f(gib[jj + 512]) + bih[jj + 512];
        float in_ = bf2f(gib[jj + 1024]) + bih[jj + 1024];
        float hr = bf2f(ghb[jj]) + bhh[jj];
        float hz = bf2f(ghb[jj + 512]) + bhh[jj + 512];
        float hn = bf2f(ghb[jj + 1024]) + bhh[jj + 1024];
        float r = fast_sigmoid(ir + hr);
        float z = fast_sigmoid(iz + hz);
        float n = fast_tanh(in_ + r * hn);
        float h = hfp[u];
        h = (1.0f - z) * n + z * h;
        hfp[u] = h;
        hbp[u] = f2bf(h);
    }
}

// ---------- to_probs: softmax(relu(h @ W_pr^T + b_pr)), one wave per row ----------
__global__ __launch_bounds__(256) void probs_kernel(const float* __restrict__ h,
                                                    const float* __restrict__ Wpr,
                                                    const float* __restrict__ bpr,
                                                    float* __restrict__ out) {
    const int row = blockIdx.x * 4 + (threadIdx.x >> 6);
    const int lane = threadIdx.x & 63;
    const float* hr = h + (size_t)row * 512;
    float p0 = 0.f, p1 = 0.f, p2 = 0.f;
#pragma unroll
    for (int i = 0; i < 8; ++i) {
        int k = lane + i * 64;
        float x = hr[k];
        p0 += x * Wpr[k];
        p1 += x * Wpr[512 + k];
        p2 += x * Wpr[1024 + k];
    }
#pragma unroll
    for (int off = 32; off; off >>= 1) {
        p0 += __shfl_down(p0, off, 64);
        p1 += __shfl_down(p1, off, 64);
        p2 += __shfl_down(p2, off, 64);
    }
    if (lane == 0) {
        p0 = fmaxf(p0 + bpr[0], 0.f);
        p1 = fmaxf(p1 + bpr[1], 0.f);
        p2 = fmaxf(p2 + bpr[2], 0.f);
        float m = fmaxf(p0, fmaxf(p1, p2));
        float e0 = __expf(p0 - m), e1 = __expf(p1 - m), e2 = __expf(p2 - m);
        float inv = 1.0f / (e0 + e1 + e2);
        out[row * 3 + 0] = e0 * inv;
        out[row * 3 + 1] = e1 * inv;
        out[row * 3 + 2] = e2 * inv;
    }
}

extern "C" void kernel_launch(void* const* d_in, const int* in_sizes, int n_in,
                              void* d_out, int out_size, void* d_ws, size_t ws_size,
                              hipStream_t stream) {
    const float* obs   = (const float*)d_in[0];   // [4096,4096]
    const float* nbr   = (const float*)d_in[1];   // [4096,8,512]
    const int*   cnt   = (const int*)d_in[2];     // [4096]
    const float* W_ds  = (const float*)d_in[3];   // [1024,4096]
    const float* b_ds  = (const float*)d_in[4];
    const float* W_pol = (const float*)d_in[5];   // [512,1024]
    const float* b_pol = (const float*)d_in[6];
    const float* W_v   = (const float*)d_in[7];   // [1,1024]
    const float* b_v   = (const float*)d_in[8];
    const float* W_ih  = (const float*)d_in[9];   // [1536,512]
    const float* b_ih  = (const float*)d_in[10];
    const float* W_hh  = (const float*)d_in[11];  // [1536,512]
    const float* b_hh  = (const float*)d_in[12];
    const float* W_pr  = (const float*)d_in[13];  // [3,512]
    const float* b_pr  = (const float*)d_in[14];
    float* out = (float*)d_out;  // [4096*3 probs][4096 state_vals]

    // workspace layout (elements)
    ushort* obs_b  = (ushort*)d_ws;            // 16777216
    ushort* nbr_b  = obs_b + 16777216;         // 16777216
    ushort* Wds_b  = nbr_b + 16777216;         // 4194304
    ushort* Wpol_b = Wds_b + 4194304;          // 524288
    ushort* Wih_b  = Wpol_b + 524288;          // 786432
    ushort* Whh_b  = Wih_b + 786432;           // 786432
    ushort* enc_b  = Whh_b + 786432;           // 4194304
    ushort* h_b    = enc_b + 4194304;          // 2097152
    ushort* gi_b   = h_b + 2097152;            // 6291456
    ushort* gh_b   = gi_b + 6291456;           // 6291456
    float*  h_f    = (float*)(gh_b + 6291456); // 2097152 floats
    // total: ~126 MB

    // 1) convert inputs/weights to bf16
    cvt_f32_bf16<<<16384, 256, 0, stream>>>(obs, obs_b, 4194304);
    cvt_f32_bf16<<<16384, 256, 0, stream>>>(nbr, nbr_b, 4194304);
    cvt_f32_bf16<<<4096, 256, 0, stream>>>(W_ds, Wds_b, 1048576);
    cvt_f32_bf16<<<512, 256, 0, stream>>>(W_pol, Wpol_b, 131072);
    cvt_f32_bf16<<<768, 256, 0, stream>>>(W_ih, Wih_b, 196608);
    cvt_f32_bf16<<<768, 256, 0, stream>>>(W_hh, Whh_b, 196608);

    // 2) enc = relu(obs @ W_ds^T + b_ds)   M=4096 N=1024 K=4096
    gemm_bt<1><<<dim3(8, 32), 256, 0, stream>>>(obs_b, 4096, Wds_b, 4096, b_ds,
                                                enc_b, nullptr, 1024, 4096);
    // 3) pol = relu(enc @ W_pol^T + b_pol) -> h (fp32 master + bf16)  M=4096 N=512 K=1024
    gemm_bt<2><<<dim3(4, 32), 256, 0, stream>>>(enc_b, 1024, Wpol_b, 1024, b_pol,
                                                h_b, h_f, 512, 1024);
    // 4) state_vals
    v_kernel<<<1024, 256, 0, stream>>>(enc_b, W_v, b_v, out + 12288);

    // 5) GRU over 8 neighbor slots
    for (int t = 0; t < 8; ++t) {
        // gi = x_t @ W_ih^T   (x_t rows strided by 8*512 inside neighbors)
        gemm_bt<0><<<dim3(12, 32), 256, 0, stream>>>(nbr_b + t * 512, 4096, Wih_b, 512,
                                                     nullptr, gi_b, nullptr, 1536, 512);
        // gh = h @ W_hh^T
        gemm_bt<0><<<dim3(12, 32), 256, 0, stream>>>(h_b, 512, Whh_b, 512,
                                                     nullptr, gh_b, nullptr, 1536, 512);
        gate_kernel<<<4096, 256, 0, stream>>>(gi_b, gh_b, b_ih, b_hh, h_f, h_b, cnt, t);
    }

    // 6) probs
    probs_kernel<<<1024, 256, 0, stream>>>(h_f, W_pr, b_pr, out);
}

// Round 2
// 624.490 us; speedup vs baseline: 1.0112x; 1.0112x over previous
//
#include <hip/hip_runtime.h>
#include <hip/hip_bf16.h>

// ---------- common helpers ----------
typedef __attribute__((ext_vector_type(8))) short short8;
typedef __attribute__((ext_vector_type(4))) float floatx4;

__device__ __forceinline__ ushort f2bf(float x) {
    unsigned u = __float_as_uint(x);
    unsigned r = (u + 0x7fffu + ((u >> 16) & 1u)) >> 16;
    return (ushort)r;
}
__device__ __forceinline__ float bf2f(ushort h) {
    return __uint_as_float(((unsigned)h) << 16);
}
__device__ __forceinline__ float fast_sigmoid(float x) {
    return 1.0f / (1.0f + __expf(-x));
}
__device__ __forceinline__ float fast_tanh(float x) {
    x = fminf(fmaxf(x, -15.0f), 15.0f);
    float e = __expf(2.0f * x);
    return (e - 1.0f) / (e + 1.0f);
}
__device__ __forceinline__ void load_lds16(const void* g, void* l) {
    __builtin_amdgcn_global_load_lds(
        (__attribute__((address_space(1))) void*)(g),
        (__attribute__((address_space(3))) void*)(l),
        16, 0, 0);
}

// ---------- fp32 -> bf16 conversion ----------
__global__ __launch_bounds__(256) void cvt_f32_bf16(const float* __restrict__ src,
                                                    ushort* __restrict__ dst, int n4) {
    int i = blockIdx.x * blockDim.x + threadIdx.x;
    if (i >= n4) return;
    const float4 v = ((const float4*)src)[i];
    ushort4 o;
    o.x = f2bf(v.x); o.y = f2bf(v.y); o.z = f2bf(v.z); o.w = f2bf(v.w);
    ((ushort4*)dst)[i] = o;
}

// ---------- GEMM: C[M,N] = A[M,K] * B[N,K]^T  (both bf16, fp32 accum) ----------
// MODE 0: plain, store bf16
// MODE 1: +bias, relu, store bf16
// MODE 2: +bias, relu, store bf16 AND fp32
// BM in {64,128}, BN == 128. BM=128: waves 2x2 (64x64 each). BM=64: waves 1x4 (64x32 each).
template <int MODE, int BM, int BN>
__global__ __launch_bounds__(256) void gemm_bt(
    const ushort* __restrict__ A, int lda,
    const ushort* __restrict__ B, int ldb,
    const float* __restrict__ bias,
    ushort* __restrict__ Cb, float* __restrict__ Cf, int ldc,
    int K) {
    __shared__ __attribute__((aligned(16))) ushort sA[BM * 64];
    __shared__ __attribute__((aligned(16))) ushort sB[BN * 64];

    constexpr int NJ = (BM == 128) ? 4 : 2;   // 16-col tiles per wave
    constexpr int CAW = BM / 32;              // A staging chunks per wave
    constexpr int CBW = BN / 32;              // B staging chunks per wave

    const int tid = threadIdx.x;
    const int lane = tid & 63;
    const int w = tid >> 6;          // wave 0..3
    const int m0 = blockIdx.y * BM;
    const int n0 = blockIdx.x * BN;
    const int wm = (BM == 128) ? (w >> 1) * 64 : 0;
    const int wn = (BM == 128) ? (w & 1) * 64 : w * 32;

    const int lrow = lane >> 3;        // 0..7
    const int lcol = (lane & 7) * 8;   // 0..56 step 8

    floatx4 acc[4][NJ] = {};

    for (int k0 = 0; k0 < K; k0 += 64) {
#pragma unroll
        for (int j = 0; j < CAW; ++j) {
            int idx = w * CAW + j;
            const ushort* ga = A + (size_t)(m0 + idx * 8 + lrow) * lda + k0 + lcol;
            load_lds16(ga, &sA[idx * 512]);
        }
#pragma unroll
        for (int j = 0; j < CBW; ++j) {
            int idx = w * CBW + j;
            const ushort* gb = B + (size_t)(n0 + idx * 8 + lrow) * ldb + k0 + lcol;
            load_lds16(gb, &sB[idx * 512]);
        }
        __syncthreads();  // drains vmcnt (global_load_lds) per HIP barrier semantics
#pragma unroll
        for (int kk = 0; kk < 2; ++kk) {
            const int col = kk * 32 + (lane >> 4) * 8;
            short8 a[4], b[NJ];
#pragma unroll
            for (int i = 0; i < 4; ++i)
                a[i] = *(const short8*)&sA[(wm + i * 16 + (lane & 15)) * 64 + col];
#pragma unroll
            for (int j = 0; j < NJ; ++j)
                b[j] = *(const short8*)&sB[(wn + j * 16 + (lane & 15)) * 64 + col];
#pragma unroll
            for (int i = 0; i < 4; ++i)
#pragma unroll
                for (int j = 0; j < NJ; ++j)
                    acc[i][j] = __builtin_amdgcn_mfma_f32_16x16x32_bf16(a[i], b[j], acc[i][j], 0, 0, 0);
        }
        __syncthreads();
    }

    // epilogue: C/D layout row=(lane>>4)*4+reg, col=lane&15
    const int ml = (lane >> 4) * 4;
    const int nl = lane & 15;
#pragma unroll
    for (int j = 0; j < NJ; ++j) {
        const int n = n0 + wn + j * 16 + nl;
        float bv = 0.0f;
        if (MODE > 0) bv = bias[n];
#pragma unroll
        for (int i = 0; i < 4; ++i) {
            const int mbase = m0 + wm + i * 16 + ml;
#pragma unroll
            for (int r = 0; r < 4; ++r) {
                float v = acc[i][j][r];
                if (MODE > 0) { v += bv; v = fmaxf(v, 0.0f); }
                size_t off = (size_t)(mbase + r) * ldc + n;
                Cb[off] = f2bf(v);
                if (MODE == 2) Cf[off] = v;
            }
        }
    }
}

// ---------- fused GRU step: gi & gh GEMMs + gates + masked h update ----------
// Grid (4 slabs, 64 M-blocks), 256 threads. Slab s owns h-cols [s*128, s*128+128).
// Wave w owns h-cols [s*128+w*32, +32). Per wave: 16 rz tiles (shared acc for
// gi+gh of r,z gates) + 8 in tiles + 8 hn tiles. K-tile = 32.
__global__ __launch_bounds__(256) void gru_step(
    const ushort* __restrict__ X,    // nbr_b + t*512, row stride 4096
    const ushort* __restrict__ H,    // h_b [4096,512] bf16
    const ushort* __restrict__ Wih,  // [1536,512] bf16
    const ushort* __restrict__ Whh,  // [1536,512] bf16
    const float* __restrict__ bih, const float* __restrict__ bhh,
    const int* __restrict__ cnt,
    float* __restrict__ hf, ushort* __restrict__ hb, int t) {
    __shared__ __attribute__((aligned(16))) ushort sX[64 * 32];     // 4 KB
    __shared__ __attribute__((aligned(16))) ushort sH[64 * 32];     // 4 KB
    __shared__ __attribute__((aligned(16))) ushort sBih[384 * 32];  // 24 KB
    __shared__ __attribute__((aligned(16))) ushort sBhh[384 * 32];  // 24 KB
    __shared__ int scnt[64];

    const int tid = threadIdx.x;
    const int lane = tid & 63;
    const int w = tid >> 6;
    const int s = blockIdx.x;        // slab 0..3
    const int m0 = blockIdx.y * 64;  // batch-row base

    if (tid < 64) scnt[tid] = cnt[m0 + tid];

    const int nl = lane & 15;
    const int ml = (lane >> 4) * 4;

    // acc init with biases (value depends only on output column)
    floatx4 acc_rz[4][4], acc_in[4][2], acc_hn[4][2];
#pragma unroll
    for (int j = 0; j < 4; ++j) {
        const int gcol = (j >> 1) * 512 + s * 128 + w * 32 + (j & 1) * 16 + nl;
        const float v = bih[gcol] + bhh[gcol];
        const floatx4 vv = {v, v, v, v};
#pragma unroll
        for (int i = 0; i < 4; ++i) acc_rz[i][j] = vv;
    }
#pragma unroll
    for (int jc = 0; jc < 2; ++jc) {
        const int ncol = 1024 + s * 128 + w * 32 + jc * 16 + nl;
        const float vi = bih[ncol];
        const float vh = bhh[ncol];
        const floatx4 vvi = {vi, vi, vi, vi};
        const floatx4 vvh = {vh, vh, vh, vh};
#pragma unroll
        for (int i = 0; i < 4; ++i) { acc_in[i][jc] = vvi; acc_hn[i][jc] = vvh; }
    }

    const int lrow = lane >> 2;        // 0..15
    const int lcol = (lane & 3) * 8;   // 0,8,16,24

    for (int k0 = 0; k0 < 512; k0 += 32) {
        // stage A (X and H): 4 chunks each of 16 rows x 32 cols; wave w takes chunk w
        load_lds16(X + (size_t)(m0 + w * 16 + lrow) * 4096 + k0 + lcol, &sX[w * 512]);
        load_lds16(H + (size_t)(m0 + w * 16 + lrow) * 512 + k0 + lcol, &sH[w * 512]);
        // stage B (both weights): 24 chunks each; wave w takes chunks [w*6, w*6+6)
#pragma unroll
        for (int j = 0; j < 6; ++j) {
            const int ci = w * 6 + j;
            const int nh = ci * 16 + lrow;                      // 0..383
            const int grow = (nh >> 7) * 512 + s * 128 + (nh & 127);
            load_lds16(Wih + (size_t)grow * 512 + k0 + lcol, &sBih[ci * 512]);
            load_lds16(Whh + (size_t)grow * 512 + k0 + lcol, &sBhh[ci * 512]);
        }
        __syncthreads();

        const int colq = (lane >> 4) * 8;
        short8 ax[4], ah[4], bi[6], bh[6];
#pragma unroll
        for (int i = 0; i < 4; ++i) {
            ax[i] = *(const short8*)&sX[(i * 16 + nl) * 32 + colq];
            ah[i] = *(const short8*)&sH[(i * 16 + nl) * 32 + colq];
        }
#pragma unroll
        for (int jj = 0; jj < 6; ++jj) {
            const int br = (jj >> 1) * 128 + w * 32 + (jj & 1) * 16 + nl;
            bi[jj] = *(const short8*)&sBih[br * 32 + colq];
            bh[jj] = *(const short8*)&sBhh[br * 32 + colq];
        }
#pragma unroll
        for (int i = 0; i < 4; ++i) {
#pragma unroll
            for (int j = 0; j < 4; ++j) {
                acc_rz[i][j] = __builtin_amdgcn_mfma_f32_16x16x32_bf16(ax[i], bi[j], acc_rz[i][j], 0, 0, 0);
                acc_rz[i][j] = __builtin_amdgcn_mfma_f32_16x16x32_bf16(ah[i], bh[j], acc_rz[i][j], 0, 0, 0);
            }
#pragma unroll
            for (int jc = 0; jc < 2; ++jc) {
                acc_in[i][jc] = __builtin_amdgcn_mfma_f32_16x16x32_bf16(ax[i], bi[4 + jc], acc_in[i][jc], 0, 0, 0);
                acc_hn[i][jc] = __builtin_amdgcn_mfma_f32_16x16x32_bf16(ah[i], bh[4 + jc], acc_hn[i][jc], 0, 0, 0);
            }
        }
        __syncthreads();
    }

    // epilogue: gates + masked update. C/D layout row=(lane>>4)*4+reg, col=lane&15
#pragma unroll
    for (int i = 0; i < 4; ++i) {
#pragma unroll
        for (int jc = 0; jc < 2; ++jc) {
            const int col = s * 128 + w * 32 + jc * 16 + nl;
#pragma unroll
            for (int r = 0; r < 4; ++r) {
                const int lr = i * 16 + ml + r;      // 0..63
                const int row = m0 + lr;
                const float rg = fast_sigmoid(acc_rz[i][jc][r]);
                const float zg = fast_sigmoid(acc_rz[i][2 + jc][r]);
                const float ng = fast_tanh(acc_in[i][jc][r] + rg * acc_hn[i][jc][r]);
                const size_t off = (size_t)row * 512 + col;
                const float ho = hf[off];
                const float hv = (t < scnt[lr]) ? ((1.0f - zg) * ng + zg * ho) : ho;
                hf[off] = hv;
                hb[off] = f2bf(hv);
            }
        }
    }
}

// ---------- v_net: tanh(enc @ W_v^T + b_v), one wave per row ----------
__global__ __launch_bounds__(256) void v_kernel(const ushort* __restrict__ enc,
                                                const float* __restrict__ Wv,
                                                const float* __restrict__ bv,
                                                float* __restrict__ out) {
    const int row = blockIdx.x * 4 + (threadIdx.x >> 6);
    const int lane = threadIdx.x & 63;
    const ushort* e = enc + (size_t)row * 1024;
    float s = 0.0f;
#pragma unroll
    for (int i = 0; i < 16; ++i) {
        int k = lane + i * 64;
        s += bf2f(e[k]) * Wv[k];
    }
#pragma unroll
    for (int off = 32; off; off >>= 1) s += __shfl_down(s, off, 64);
    if (lane == 0) out[row] = fast_tanh(s + bv[0]);
}

// ---------- to_probs: softmax(relu(h @ W_pr^T + b_pr)), one wave per row ----------
__global__ __launch_bounds__(256) void probs_kernel(const float* __restrict__ h,
                                                    const float* __restrict__ Wpr,
                                                    const float* __restrict__ bpr,
                                                    float* __restrict__ out) {
    const int row = blockIdx.x * 4 + (threadIdx.x >> 6);
    const int lane = threadIdx.x & 63;
    const float* hr = h + (size_t)row * 512;
    float p0 = 0.f, p1 = 0.f, p2 = 0.f;
#pragma unroll
    for (int i = 0; i < 8; ++i) {
        int k = lane + i * 64;
        float x = hr[k];
        p0 += x * Wpr[k];
        p1 += x * Wpr[512 + k];
        p2 += x * Wpr[1024 + k];
    }
#pragma unroll
    for (int off = 32; off; off >>= 1) {
        p0 += __shfl_down(p0, off, 64);
        p1 += __shfl_down(p1, off, 64);
        p2 += __shfl_down(p2, off, 64);
    }
    if (lane == 0) {
        p0 = fmaxf(p0 + bpr[0], 0.f);
        p1 = fmaxf(p1 + bpr[1], 0.f);
        p2 = fmaxf(p2 + bpr[2], 0.f);
        float m = fmaxf(p0, fmaxf(p1, p2));
        float e0 = __expf(p0 - m), e1 = __expf(p1 - m), e2 = __expf(p2 - m);
        float inv = 1.0f / (e0 + e1 + e2);
        out[row * 3 + 0] = e0 * inv;
        out[row * 3 + 1] = e1 * inv;
        out[row * 3 + 2] = e2 * inv;
    }
}

extern "C" void kernel_launch(void* const* d_in, const int* in_sizes, int n_in,
                              void* d_out, int out_size, void* d_ws, size_t ws_size,
                              hipStream_t stream) {
    const float* obs   = (const float*)d_in[0];   // [4096,4096]
    const float* nbr   = (const float*)d_in[1];   // [4096,8,512]
    const int*   cnt   = (const int*)d_in[2];     // [4096]
    const float* W_ds  = (const float*)d_in[3];   // [1024,4096]
    const float* b_ds  = (const float*)d_in[4];
    const float* W_pol = (const float*)d_in[5];   // [512,1024]
    const float* b_pol = (const float*)d_in[6];
    const float* W_v   = (const float*)d_in[7];   // [1,1024]
    const float* b_v   = (const float*)d_in[8];
    const float* W_ih  = (const float*)d_in[9];   // [1536,512]
    const float* b_ih  = (const float*)d_in[10];
    const float* W_hh  = (const float*)d_in[11];  // [1536,512]
    const float* b_hh  = (const float*)d_in[12];
    const float* W_pr  = (const float*)d_in[13];  // [3,512]
    const float* b_pr  = (const float*)d_in[14];
    float* out = (float*)d_out;  // [4096*3 probs][4096 state_vals]

    // workspace layout (ushort elements)
    ushort* obs_b  = (ushort*)d_ws;            // 16777216
    ushort* nbr_b  = obs_b + 16777216;         // 16777216
    ushort* Wds_b  = nbr_b + 16777216;         // 4194304
    ushort* Wpol_b = Wds_b + 4194304;          // 524288
    ushort* Wih_b  = Wpol_b + 524288;          // 786432
    ushort* Whh_b  = Wih_b + 786432;           // 786432
    ushort* enc_b  = Whh_b + 786432;           // 4194304
    ushort* h_b    = enc_b + 4194304;          // 2097152
    float*  h_f    = (float*)(h_b + 2097152);  // 2097152 floats
    // total ~109 MB

    // 1) convert inputs/weights to bf16
    cvt_f32_bf16<<<16384, 256, 0, stream>>>(obs, obs_b, 4194304);
    cvt_f32_bf16<<<16384, 256, 0, stream>>>(nbr, nbr_b, 4194304);
    cvt_f32_bf16<<<4096, 256, 0, stream>>>(W_ds, Wds_b, 1048576);
    cvt_f32_bf16<<<512, 256, 0, stream>>>(W_pol, Wpol_b, 131072);
    cvt_f32_bf16<<<768, 256, 0, stream>>>(W_ih, Wih_b, 196608);
    cvt_f32_bf16<<<768, 256, 0, stream>>>(W_hh, Whh_b, 196608);

    // 2) enc = relu(obs @ W_ds^T + b_ds)   M=4096 N=1024 K=4096, 64x128 tiles -> 512 blocks
    gemm_bt<1, 64, 128><<<dim3(8, 64), 256, 0, stream>>>(obs_b, 4096, Wds_b, 4096, b_ds,
                                                         enc_b, nullptr, 1024, 4096);
    // 3) pol = relu(enc @ W_pol^T + b_pol) -> h (fp32 master + bf16)  M=4096 N=512 K=1024
    gemm_bt<2, 64, 128><<<dim3(4, 64), 256, 0, stream>>>(enc_b, 1024, Wpol_b, 1024, b_pol,
                                                         h_b, h_f, 512, 1024);
    // 4) state_vals
    v_kernel<<<1024, 256, 0, stream>>>(enc_b, W_v, b_v, out + 12288);

    // 5) GRU: 8 fused steps (gi+gh GEMMs + gates + masked update)
    for (int t = 0; t < 8; ++t) {
        gru_step<<<dim3(4, 64), 256, 0, stream>>>(nbr_b + t * 512, h_b, Wih_b, Whh_b,
                                                  b_ih, b_hh, cnt, h_f, h_b, t);
    }

    // 6) probs
    probs_kernel<<<1024, 256, 0, stream>>>(h_f, W_pr, b_pr, out);
}

// Round 3
// 463.434 us; speedup vs baseline: 1.3626x; 1.3475x over previous
//
#include <hip/hip_runtime.h>
#include <hip/hip_bf16.h>

// ---------- common helpers ----------
typedef __attribute__((ext_vector_type(8))) short short8;
typedef __attribute__((ext_vector_type(4))) float floatx4;

__device__ __forceinline__ ushort f2bf(float x) {
    unsigned u = __float_as_uint(x);
    unsigned r = (u + 0x7fffu + ((u >> 16) & 1u)) >> 16;
    return (ushort)r;
}
__device__ __forceinline__ float bf2f(ushort h) {
    return __uint_as_float(((unsigned)h) << 16);
}
__device__ __forceinline__ float fast_sigmoid(float x) {
    return 1.0f / (1.0f + __expf(-x));
}
__device__ __forceinline__ float fast_tanh(float x) {
    x = fminf(fmaxf(x, -15.0f), 15.0f);
    float e = __expf(2.0f * x);
    return (e - 1.0f) / (e + 1.0f);
}
__device__ __forceinline__ void load_lds16(const void* g, void* l) {
    __builtin_amdgcn_global_load_lds(
        (__attribute__((address_space(1))) void*)(g),
        (__attribute__((address_space(3))) void*)(l),
        16, 0, 0);
}

// ---------- swizzled LDS tile: units of 8 rows x 64 cols (1 KB) ----------
// Physical layout within a unit: byte addr = r*128 + (c ^ r)*16, r=row&7, c=chunk (16B col group).
// Staging: lane L writes LDS base+L*16 (HW-fixed); we permute the *global* source so that
// lane L = r*8+cp fetches logical chunk c = cp ^ r. Reads then hit all 32 banks per 8 lanes
// (2-way alias over 16 lanes = free per m136).
__device__ __forceinline__ void stage_unit(const ushort* grow0, int ld, ushort* lds_unit) {
    const int lane = threadIdx.x & 63;
    const int r = lane >> 3;
    const int c = (lane & 7) ^ r;
    load_lds16(grow0 + (size_t)r * ld + c * 8, lds_unit);
}
__device__ __forceinline__ short8 lds_read8(const ushort* buf, int R, int c_el) {
    const int idx = ((R >> 3) << 9) + ((R & 7) << 6) + ((((c_el >> 3) ^ (R & 7))) << 3);
    return *(const short8*)(buf + idx);
}

// ---------- fp32 -> bf16 conversion ----------
__global__ __launch_bounds__(256) void cvt_f32_bf16(const float* __restrict__ src,
                                                    ushort* __restrict__ dst, int n4) {
    int i = blockIdx.x * blockDim.x + threadIdx.x;
    if (i >= n4) return;
    const float4 v = ((const float4*)src)[i];
    ushort4 o;
    o.x = f2bf(v.x); o.y = f2bf(v.y); o.z = f2bf(v.z); o.w = f2bf(v.w);
    ((ushort4*)dst)[i] = o;
}

// ---------- GEMM: C[M,N] = A[M,K] * B[N,K]^T, BM=64, swizzled LDS ----------
// MODE 2: +bias, relu, store bf16 AND fp32 (KSPLIT must be 1)
// MODE 3: fp32 partial store (split-K), no bias/act
// BN=256: wave owns 64 cols (4 tiles). BN=128: wave owns 32 cols (2 tiles). All waves cover all 64 rows.
template <int MODE, int BN, int KSPLIT>
__global__ __launch_bounds__(256, 2) void gemm64(
    const ushort* __restrict__ A, int lda,
    const ushort* __restrict__ B, int ldb,
    const float* __restrict__ bias,
    ushort* __restrict__ Cb, float* __restrict__ Cf, int ldc,
    int K, size_t part_stride) {
    __shared__ __attribute__((aligned(16))) ushort sA[64 * 64];
    __shared__ __attribute__((aligned(16))) ushort sB[BN * 64];

    constexpr int NJ = BN / 64;       // 16-col tiles per wave (4 or 2)
    constexpr int UB = BN / 32;       // B units per wave (8 or 4)

    const int tid = threadIdx.x;
    const int lane = tid & 63;
    const int w = tid >> 6;
    const int m0 = blockIdx.y * 64;
    const int n0 = blockIdx.x * BN;
    const int wn = w * (16 * NJ);
    const int nl = lane & 15;

    const int Kper = K / KSPLIT;
    const int kbase = (KSPLIT > 1) ? blockIdx.z * Kper : 0;
    if (MODE == 3) Cf += (size_t)blockIdx.z * part_stride;

    floatx4 acc[4][NJ] = {};

    for (int k0 = kbase; k0 < kbase + Kper; k0 += 64) {
#pragma unroll
        for (int u = 0; u < 2; ++u) {
            const int ua = w * 2 + u;
            stage_unit(A + (size_t)(m0 + ua * 8) * lda + k0, lda, &sA[ua * 512]);
        }
#pragma unroll
        for (int u = 0; u < UB; ++u) {
            const int ub = w * UB + u;
            stage_unit(B + (size_t)(n0 + ub * 8) * ldb + k0, ldb, &sB[ub * 512]);
        }
        __syncthreads();  // drains vmcnt per HIP barrier semantics
#pragma unroll
        for (int kk = 0; kk < 2; ++kk) {
            const int cb = kk * 32 + (lane >> 4) * 8;
            short8 a[4], b[NJ];
#pragma unroll
            for (int i = 0; i < 4; ++i) a[i] = lds_read8(sA, i * 16 + nl, cb);
#pragma unroll
            for (int j = 0; j < NJ; ++j) b[j] = lds_read8(sB, wn + j * 16 + nl, cb);
#pragma unroll
            for (int i = 0; i < 4; ++i)
#pragma unroll
                for (int j = 0; j < NJ; ++j)
                    acc[i][j] = __builtin_amdgcn_mfma_f32_16x16x32_bf16(a[i], b[j], acc[i][j], 0, 0, 0);
        }
        __syncthreads();
    }

    // epilogue: C/D layout row=(lane>>4)*4+reg, col=lane&15
    const int ml = (lane >> 4) * 4;
#pragma unroll
    for (int j = 0; j < NJ; ++j) {
        const int n = n0 + wn + j * 16 + nl;
        float bv = 0.0f;
        if (MODE == 2) bv = bias[n];
#pragma unroll
        for (int i = 0; i < 4; ++i) {
            const int mbase = m0 + i * 16 + ml;
#pragma unroll
            for (int r = 0; r < 4; ++r) {
                float v = acc[i][j][r];
                const size_t off = (size_t)(mbase + r) * ldc + n;
                if (MODE == 2) {
                    v += bv; v = fmaxf(v, 0.0f);
                    Cb[off] = f2bf(v);
                    Cf[off] = v;
                } else {
                    Cf[off] = v;
                }
            }
        }
    }
}

// ---------- split-K combine: enc = relu(p0 + p1 + bias) -> bf16 ----------
__global__ __launch_bounds__(256) void combine_relu(const float* __restrict__ p0,
                                                    const float* __restrict__ p1,
                                                    const float* __restrict__ bias,
                                                    ushort* __restrict__ ob, int n4) {
    int i = blockIdx.x * blockDim.x + threadIdx.x;
    if (i >= n4) return;
    const float4 a = ((const float4*)p0)[i];
    const float4 b = ((const float4*)p1)[i];
    const int col = (i * 4) & 1023;
    const float4 bs = *(const float4*)(bias + col);
    ushort4 o;
    o.x = f2bf(fmaxf(a.x + b.x + bs.x, 0.f));
    o.y = f2bf(fmaxf(a.y + b.y + bs.y, 0.f));
    o.z = f2bf(fmaxf(a.z + b.z + bs.z, 0.f));
    o.w = f2bf(fmaxf(a.w + b.w + bs.w, 0.f));
    ((ushort4*)ob)[i] = o;
}

// ---------- fused GRU step: gi & gh GEMMs + gates + masked h update ----------
// Grid (8 col-slabs, 64 row-blocks). Block = 64 rows x 64 h-cols. Wave w owns cols
// [s*64+w*16, +16) for ALL gates: accs r/z/in/hn x 4 row-tiles = 16 floatx4 (64 VGPR).
// h ping-pong: reads Hin (step t state), writes Hout — no intra-launch race.
__global__ __launch_bounds__(256, 2) void gru_step(
    const ushort* __restrict__ X,    // nbr_b + t*512, row stride 4096
    const ushort* __restrict__ Hin,  // [4096,512] bf16
    const ushort* __restrict__ Wih,  // [1536,512] bf16
    const ushort* __restrict__ Whh,  // [1536,512] bf16
    const float* __restrict__ bih, const float* __restrict__ bhh,
    const int* __restrict__ cnt,
    float* __restrict__ hf, ushort* __restrict__ Hout, int t) {
    __shared__ __attribute__((aligned(16))) ushort sX[64 * 64];     // 8 KB
    __shared__ __attribute__((aligned(16))) ushort sH[64 * 64];     // 8 KB
    __shared__ __attribute__((aligned(16))) ushort sBih[192 * 64];  // 24 KB
    __shared__ __attribute__((aligned(16))) ushort sBhh[192 * 64];  // 24 KB
    __shared__ int scnt[64];

    const int tid = threadIdx.x;
    const int lane = tid & 63;
    const int w = tid >> 6;
    const int s = blockIdx.x;        // col slab 0..7
    const int m0 = blockIdx.y * 64;  // batch-row base

    if (tid < 64) scnt[tid] = cnt[m0 + tid];

    const int nl = lane & 15;
    const int ml = (lane >> 4) * 4;
    const int col = s * 64 + w * 16 + nl;  // this lane's h column

    // acc init with biases (depends only on column)
    floatx4 accr[4], accz[4], accn[4], acch[4];
    {
        const float br_ = bih[col] + bhh[col];
        const float bz_ = bih[512 + col] + bhh[512 + col];
        const float bn_i = bih[1024 + col];
        const float bn_h = bhh[1024 + col];
        const floatx4 vr = {br_, br_, br_, br_};
        const floatx4 vz = {bz_, bz_, bz_, bz_};
        const floatx4 vi = {bn_i, bn_i, bn_i, bn_i};
        const floatx4 vh = {bn_h, bn_h, bn_h, bn_h};
#pragma unroll
        for (int i = 0; i < 4; ++i) { accr[i] = vr; accz[i] = vz; accn[i] = vi; acch[i] = vh; }
    }

    for (int k0 = 0; k0 < 512; k0 += 64) {
        // A tiles: sX/sH 8 units each; wave stages 2 of each
#pragma unroll
        for (int u = 0; u < 2; ++u) {
            const int ua = w * 2 + u;
            stage_unit(X + (size_t)(m0 + ua * 8) * 4096 + k0, 4096, &sX[ua * 512]);
            stage_unit(Hin + (size_t)(m0 + ua * 8) * 512 + k0, 512, &sH[ua * 512]);
        }
        // weight slabs: 24 units each (192 rows: gate g -> rows g*512 + s*64 + 0..63)
#pragma unroll
        for (int j = 0; j < 6; ++j) {
            const int u = w * 6 + j;
            const int grow0 = (u >> 3) * 512 + s * 64 + (u & 7) * 8;
            stage_unit(Wih + (size_t)grow0 * 512 + k0, 512, &sBih[u * 512]);
            stage_unit(Whh + (size_t)grow0 * 512 + k0, 512, &sBhh[u * 512]);
        }
        __syncthreads();
#pragma unroll
        for (int kk = 0; kk < 2; ++kk) {
            const int cb = kk * 32 + (lane >> 4) * 8;
            short8 ax[4], ah[4];
#pragma unroll
            for (int i = 0; i < 4; ++i) {
                ax[i] = lds_read8(sX, i * 16 + nl, cb);
                ah[i] = lds_read8(sH, i * 16 + nl, cb);
            }
            const short8 bir = lds_read8(sBih, w * 16 + nl, cb);
            const short8 biz = lds_read8(sBih, 64 + w * 16 + nl, cb);
            const short8 bin = lds_read8(sBih, 128 + w * 16 + nl, cb);
            const short8 bhr = lds_read8(sBhh, w * 16 + nl, cb);
            const short8 bhz = lds_read8(sBhh, 64 + w * 16 + nl, cb);
            const short8 bhn = lds_read8(sBhh, 128 + w * 16 + nl, cb);
#pragma unroll
            for (int i = 0; i < 4; ++i) {
                accr[i] = __builtin_amdgcn_mfma_f32_16x16x32_bf16(ax[i], bir, accr[i], 0, 0, 0);
                accr[i] = __builtin_amdgcn_mfma_f32_16x16x32_bf16(ah[i], bhr, accr[i], 0, 0, 0);
                accz[i] = __builtin_amdgcn_mfma_f32_16x16x32_bf16(ax[i], biz, accz[i], 0, 0, 0);
                accz[i] = __builtin_amdgcn_mfma_f32_16x16x32_bf16(ah[i], bhz, accz[i], 0, 0, 0);
                accn[i] = __builtin_amdgcn_mfma_f32_16x16x32_bf16(ax[i], bin, accn[i], 0, 0, 0);
                acch[i] = __builtin_amdgcn_mfma_f32_16x16x32_bf16(ah[i], bhn, acch[i], 0, 0, 0);
            }
        }
        __syncthreads();
    }

    // epilogue: gates + masked update
#pragma unroll
    for (int i = 0; i < 4; ++i) {
#pragma unroll
        for (int r = 0; r < 4; ++r) {
            const int lr = i * 16 + ml + r;
            const int row = m0 + lr;
            const float rg = fast_sigmoid(accr[i][r]);
            const float zg = fast_sigmoid(accz[i][r]);
            const float ng = fast_tanh(accn[i][r] + rg * acch[i][r]);
            const size_t off = (size_t)row * 512 + col;
            const float ho = hf[off];
            const float hv = (t < scnt[lr]) ? ((1.0f - zg) * ng + zg * ho) : ho;
            hf[off] = hv;
            Hout[off] = f2bf(hv);
        }
    }
}

// ---------- v_net: tanh(enc @ W_v^T + b_v), one wave per row ----------
__global__ __launch_bounds__(256) void v_kernel(const ushort* __restrict__ enc,
                                                const float* __restrict__ Wv,
                                                const float* __restrict__ bv,
                                                float* __restrict__ out) {
    const int row = blockIdx.x * 4 + (threadIdx.x >> 6);
    const int lane = threadIdx.x & 63;
    const ushort* e = enc + (size_t)row * 1024;
    float s = 0.0f;
#pragma unroll
    for (int i = 0; i < 16; ++i) {
        int k = lane + i * 64;
        s += bf2f(e[k]) * Wv[k];
    }
#pragma unroll
    for (int off = 32; off; off >>= 1) s += __shfl_down(s, off, 64);
    if (lane == 0) out[row] = fast_tanh(s + bv[0]);
}

// ---------- to_probs: softmax(relu(h @ W_pr^T + b_pr)), one wave per row ----------
__global__ __launch_bounds__(256) void probs_kernel(const float* __restrict__ h,
                                                    const float* __restrict__ Wpr,
                                                    const float* __restrict__ bpr,
                                                    float* __restrict__ out) {
    const int row = blockIdx.x * 4 + (threadIdx.x >> 6);
    const int lane = threadIdx.x & 63;
    const float* hr = h + (size_t)row * 512;
    float p0 = 0.f, p1 = 0.f, p2 = 0.f;
#pragma unroll
    for (int i = 0; i < 8; ++i) {
        int k = lane + i * 64;
        float x = hr[k];
        p0 += x * Wpr[k];
        p1 += x * Wpr[512 + k];
        p2 += x * Wpr[1024 + k];
    }
#pragma unroll
    for (int off = 32; off; off >>= 1) {
        p0 += __shfl_down(p0, off, 64);
        p1 += __shfl_down(p1, off, 64);
        p2 += __shfl_down(p2, off, 64);
    }
    if (lane == 0) {
        p0 = fmaxf(p0 + bpr[0], 0.f);
        p1 = fmaxf(p1 + bpr[1], 0.f);
        p2 = fmaxf(p2 + bpr[2], 0.f);
        float m = fmaxf(p0, fmaxf(p1, p2));
        float e0 = __expf(p0 - m), e1 = __expf(p1 - m), e2 = __expf(p2 - m);
        float inv = 1.0f / (e0 + e1 + e2);
        out[row * 3 + 0] = e0 * inv;
        out[row * 3 + 1] = e1 * inv;
        out[row * 3 + 2] = e2 * inv;
    }
}

extern "C" void kernel_launch(void* const* d_in, const int* in_sizes, int n_in,
                              void* d_out, int out_size, void* d_ws, size_t ws_size,
                              hipStream_t stream) {
    const float* obs   = (const float*)d_in[0];   // [4096,4096]
    const float* nbr   = (const float*)d_in[1];   // [4096,8,512]
    const int*   cnt   = (const int*)d_in[2];     // [4096]
    const float* W_ds  = (const float*)d_in[3];   // [1024,4096]
    const float* b_ds  = (const float*)d_in[4];
    const float* W_pol = (const float*)d_in[5];   // [512,1024]
    const float* b_pol = (const float*)d_in[6];
    const float* W_v   = (const float*)d_in[7];   // [1,1024]
    const float* b_v   = (const float*)d_in[8];
    const float* W_ih  = (const float*)d_in[9];   // [1536,512]
    const float* b_ih  = (const float*)d_in[10];
    const float* W_hh  = (const float*)d_in[11];  // [1536,512]
    const float* b_hh  = (const float*)d_in[12];
    const float* W_pr  = (const float*)d_in[13];  // [3,512]
    const float* b_pr  = (const float*)d_in[14];
    float* out = (float*)d_out;  // [4096*3 probs][4096 state_vals]

    // workspace layout (ushort elements unless noted)
    ushort* obs_b  = (ushort*)d_ws;            // 16777216 (32 MB)
    ushort* nbr_b  = obs_b + 16777216;         // 16777216 (32 MB)
    ushort* Wds_b  = nbr_b + 16777216;         // 4194304  (8 MB)
    ushort* Wpol_b = Wds_b + 4194304;          // 524288   (1 MB)
    ushort* Wih_b  = Wpol_b + 524288;          // 786432   (1.5 MB)
    ushort* Whh_b  = Wih_b + 786432;           // 786432   (1.5 MB)
    ushort* enc_b  = Whh_b + 786432;           // 4194304  (8 MB)
    ushort* h_b0   = enc_b + 4194304;          // 2097152  (4 MB)
    ushort* h_b1   = h_b0 + 2097152;           // 2097152  (4 MB)
    float*  h_f    = (float*)(h_b1 + 2097152); // 4194304 floats (16 MB) -> uses 8 MB
    float*  part   = h_f + 2097152;            // 2 x 4194304 floats (32 MB)
    // total ~124.5 MB

    // 1) convert inputs/weights to bf16
    cvt_f32_bf16<<<16384, 256, 0, stream>>>(obs, obs_b, 4194304);
    cvt_f32_bf16<<<16384, 256, 0, stream>>>(nbr, nbr_b, 4194304);
    cvt_f32_bf16<<<4096, 256, 0, stream>>>(W_ds, Wds_b, 1048576);
    cvt_f32_bf16<<<512, 256, 0, stream>>>(W_pol, Wpol_b, 131072);
    cvt_f32_bf16<<<768, 256, 0, stream>>>(W_ih, Wih_b, 196608);
    cvt_f32_bf16<<<768, 256, 0, stream>>>(W_hh, Whh_b, 196608);

    // 2) enc = relu(obs @ W_ds^T + b_ds), split-K=2: M=4096 N=1024 K=4096
    gemm64<3, 256, 2><<<dim3(4, 64, 2), 256, 0, stream>>>(
        obs_b, 4096, Wds_b, 4096, nullptr, nullptr, part, 1024, 4096, 4194304);
    combine_relu<<<4096, 256, 0, stream>>>(part, part + 4194304, b_ds, enc_b, 1048576);

    // 3) pol = relu(enc @ W_pol^T + b_pol) -> h_b0 (bf16) + h_f (fp32 master)
    gemm64<2, 128, 1><<<dim3(4, 64, 1), 256, 0, stream>>>(
        enc_b, 1024, Wpol_b, 1024, b_pol, h_b0, h_f, 512, 1024, 0);

    // 4) state_vals
    v_kernel<<<1024, 256, 0, stream>>>(enc_b, W_v, b_v, out + 12288);

    // 5) GRU: 8 fused steps, h_b ping-pong (no intra-launch read/write race)
    for (int t = 0; t < 8; ++t) {
        const ushort* hin = (t & 1) ? h_b1 : h_b0;
        ushort* hout = (t & 1) ? h_b0 : h_b1;
        gru_step<<<dim3(8, 64), 256, 0, stream>>>(nbr_b + t * 512, hin, Wih_b, Whh_b,
                                                  b_ih, b_hh, cnt, h_f, hout, t);
    }

    // 6) probs
    probs_kernel<<<1024, 256, 0, stream>>>(h_f, W_pr, b_pr, out);
}

// Round 4
// 445.562 us; speedup vs baseline: 1.4172x; 1.0401x over previous
//
#include <hip/hip_runtime.h>
#include <hip/hip_bf16.h>

// ---------- common helpers ----------
typedef __attribute__((ext_vector_type(8))) short short8;
typedef __attribute__((ext_vector_type(4))) float floatx4;

__device__ __forceinline__ ushort f2bf(float x) {
    unsigned u = __float_as_uint(x);
    unsigned r = (u + 0x7fffu + ((u >> 16) & 1u)) >> 16;
    return (ushort)r;
}
__device__ __forceinline__ float bf2f(ushort h) {
    return __uint_as_float(((unsigned)h) << 16);
}
__device__ __forceinline__ float fast_sigmoid(float x) {
    return 1.0f / (1.0f + __expf(-x));
}
__device__ __forceinline__ float fast_tanh(float x) {
    x = fminf(fmaxf(x, -15.0f), 15.0f);
    float e = __expf(2.0f * x);
    return (e - 1.0f) / (e + 1.0f);
}
__device__ __forceinline__ void load_lds16(const void* g, void* l) {
    __builtin_amdgcn_global_load_lds(
        (__attribute__((address_space(1))) void*)(g),
        (__attribute__((address_space(3))) void*)(l),
        16, 0, 0);
}

// ---------- swizzled LDS tile: units of 8 rows x 64 cols (1 KB) ----------
// Physical: unit row r holds logical 16B-chunk lc at chunk slot lc^r (conflict-free, verified r3:
// SQ_LDS_BANK_CONFLICT=0). Staging lane L = r*8+cp fetches logical chunk cp^r.
__device__ __forceinline__ void stage_unit(const ushort* grow0, int ld, ushort* lds_unit) {
    const int lane = threadIdx.x & 63;
    const int r = lane >> 3;
    const int c = (lane & 7) ^ r;
    load_lds16(grow0 + (size_t)r * ld + c * 8, lds_unit);
}
__device__ __forceinline__ short8 lds_read8(const ushort* buf, int R, int c_el) {
    const int idx = ((R >> 3) << 9) + ((R & 7) << 6) + ((((c_el >> 3) ^ (R & 7))) << 3);
    return *(const short8*)(buf + idx);
}

// ---------- fp32 -> bf16 conversion ----------
__global__ __launch_bounds__(256) void cvt_f32_bf16(const float* __restrict__ src,
                                                    ushort* __restrict__ dst, int n4) {
    int i = blockIdx.x * blockDim.x + threadIdx.x;
    if (i >= n4) return;
    const float4 v = ((const float4*)src)[i];
    ushort4 o;
    o.x = f2bf(v.x); o.y = f2bf(v.y); o.z = f2bf(v.z); o.w = f2bf(v.w);
    ((ushort4*)dst)[i] = o;
}

// ---------- counting sort of rows by cnt descending ----------
// perm[sorted]=orig, inv[orig]=sorted, nact[t]=#rows with cnt>t.
__global__ __launch_bounds__(256) void sort_by_cnt(const int* __restrict__ cnt,
                                                   int* __restrict__ perm,
                                                   int* __restrict__ inv,
                                                   int* __restrict__ nact) {
    __shared__ int h[9];
    __shared__ int cur[9];
    const int tid = threadIdx.x;
    if (tid < 9) h[tid] = 0;
    __syncthreads();
    for (int i = tid; i < 4096; i += 256) atomicAdd(&h[cnt[i]], 1);
    __syncthreads();
    if (tid == 0) {
        int off = 0;
        for (int c = 8; c >= 0; --c) { cur[c] = off; off += h[c]; }
        for (int t = 0; t < 8; ++t) {
            int n = 0;
            for (int c = t + 1; c <= 8; ++c) n += h[c];
            nact[t] = n;
        }
    }
    __syncthreads();
    for (int i = tid; i < 4096; i += 256) {
        const int c = cnt[i];
        const int p = atomicAdd(&cur[c], 1);
        perm[p] = i;
        inv[i] = p;
    }
}

// ---------- GEMM: C[M,N] = A[M,K] * B[N,K]^T, BM=64, swizzled LDS ----------
// MODE 2: +bias, relu, store bf16 AND fp32 (KSPLIT must be 1); MAP: scatter C rows via row_map
// MODE 3: fp32 partial store (split-K), no bias/act
template <int MODE, int BN, int KSPLIT, bool MAP>
__global__ __launch_bounds__(256, 2) void gemm64(
    const ushort* __restrict__ A, int lda,
    const ushort* __restrict__ B, int ldb,
    const float* __restrict__ bias,
    const int* __restrict__ row_map,
    ushort* __restrict__ Cb, float* __restrict__ Cf, int ldc,
    int K, size_t part_stride) {
    __shared__ __attribute__((aligned(16))) ushort sA[64 * 64];
    __shared__ __attribute__((aligned(16))) ushort sB[BN * 64];

    constexpr int NJ = (BN + 63) / 64;  // 16-col tiles per wave (2 for BN=128, 1 for BN=64)
    constexpr int UB = BN / 32;         // B units per wave

    const int tid = threadIdx.x;
    const int lane = tid & 63;
    const int w = tid >> 6;
    const int m0 = blockIdx.y * 64;
    const int n0 = blockIdx.x * BN;
    const int wn = w * (16 * NJ);
    const int nl = lane & 15;

    const int Kper = K / KSPLIT;
    const int kbase = (KSPLIT > 1) ? blockIdx.z * Kper : 0;
    if (MODE == 3) Cf += (size_t)blockIdx.z * part_stride;

    floatx4 acc[4][NJ] = {};

    for (int k0 = kbase; k0 < kbase + Kper; k0 += 64) {
#pragma unroll
        for (int u = 0; u < 2; ++u) {
            const int ua = w * 2 + u;
            stage_unit(A + (size_t)(m0 + ua * 8) * lda + k0, lda, &sA[ua * 512]);
        }
#pragma unroll
        for (int u = 0; u < UB; ++u) {
            const int ub = w * UB + u;
            stage_unit(B + (size_t)(n0 + ub * 8) * ldb + k0, ldb, &sB[ub * 512]);
        }
        __syncthreads();  // drains vmcnt per HIP barrier semantics
#pragma unroll
        for (int kk = 0; kk < 2; ++kk) {
            const int cb = kk * 32 + (lane >> 4) * 8;
            short8 a[4], b[NJ];
#pragma unroll
            for (int i = 0; i < 4; ++i) a[i] = lds_read8(sA, i * 16 + nl, cb);
#pragma unroll
            for (int j = 0; j < NJ; ++j) b[j] = lds_read8(sB, wn + j * 16 + nl, cb);
#pragma unroll
            for (int i = 0; i < 4; ++i)
#pragma unroll
                for (int j = 0; j < NJ; ++j)
                    acc[i][j] = __builtin_amdgcn_mfma_f32_16x16x32_bf16(a[i], b[j], acc[i][j], 0, 0, 0);
        }
        __syncthreads();
    }

    // epilogue: C/D layout row=(lane>>4)*4+reg, col=lane&15
    const int ml = (lane >> 4) * 4;
#pragma unroll
    for (int j = 0; j < NJ; ++j) {
        const int n = n0 + wn + j * 16 + nl;
        float bv = 0.0f;
        if (MODE == 2) bv = bias[n];
#pragma unroll
        for (int i = 0; i < 4; ++i) {
            const int mbase = m0 + i * 16 + ml;
#pragma unroll
            for (int r = 0; r < 4; ++r) {
                float v = acc[i][j][r];
                const int mr = mbase + r;
                const int orow = MAP ? row_map[mr] : mr;
                const size_t off = (size_t)orow * ldc + n;
                if (MODE == 2) {
                    v += bv; v = fmaxf(v, 0.0f);
                    Cb[off] = f2bf(v);
                    Cf[off] = v;
                } else {
                    Cf[off] = v;
                }
            }
        }
    }
}

// ---------- split-K combine: enc = relu(p0 + p1 + bias) -> bf16 ----------
__global__ __launch_bounds__(256) void combine_relu(const float* __restrict__ p0,
                                                    const float* __restrict__ p1,
                                                    const float* __restrict__ bias,
                                                    ushort* __restrict__ ob, int n4) {
    int i = blockIdx.x * blockDim.x + threadIdx.x;
    if (i >= n4) return;
    const float4 a = ((const float4*)p0)[i];
    const float4 b = ((const float4*)p1)[i];
    const int col = (i * 4) & 1023;
    const float4 bs = *(const float4*)(bias + col);
    ushort4 o;
    o.x = f2bf(fmaxf(a.x + b.x + bs.x, 0.f));
    o.y = f2bf(fmaxf(a.y + b.y + bs.y, 0.f));
    o.z = f2bf(fmaxf(a.z + b.z + bs.z, 0.f));
    o.w = f2bf(fmaxf(a.w + b.w + bs.w, 0.f));
    ((ushort4*)ob)[i] = o;
}

// ---------- fused GRU step in SORTED row space ----------
// Grid (8 col-slabs, 64 row-blocks). Block = 64 sorted rows x 64 h-cols, all gates.
// Rows sorted by cnt desc => active rows at step t are [0, nact[t]): fully-inactive
// blocks copy Hin->Hout (8 KB) and exit; boundary block masks by position.
__global__ __launch_bounds__(256, 2) void gru_step(
    const ushort* __restrict__ Xall,  // nbr_b (orig row-major, row stride 4096), +t*512
    const ushort* __restrict__ Hin,   // [4096,512] bf16, sorted space
    const ushort* __restrict__ Wih,   // [1536,512] bf16
    const ushort* __restrict__ Whh,   // [1536,512] bf16
    const float* __restrict__ bih, const float* __restrict__ bhh,
    const int* __restrict__ perm, const int* __restrict__ nact,
    float* __restrict__ hf, ushort* __restrict__ Hout, int t) {
    __shared__ __attribute__((aligned(16))) ushort sX[64 * 64];     // 8 KB
    __shared__ __attribute__((aligned(16))) ushort sH[64 * 64];     // 8 KB
    __shared__ __attribute__((aligned(16))) ushort sBih[192 * 64];  // 24 KB
    __shared__ __attribute__((aligned(16))) ushort sBhh[192 * 64];  // 24 KB

    const int tid = threadIdx.x;
    const int lane = tid & 63;
    const int w = tid >> 6;
    const int s = blockIdx.x;        // col slab 0..7
    const int m0 = blockIdx.y * 64;  // sorted batch-row base
    const int na = nact[t];

    if (m0 >= na) {
        // fully inactive: copy h slab forward (hf is in-place, untouched)
        const int rr = tid >> 2;
        const size_t base = (size_t)(m0 + rr) * 512 + s * 64;
        const uint4* src = (const uint4*)(Hin + base);
        uint4* dst = (uint4*)(Hout + base);
        const int cc = (tid & 3) * 2;
        dst[cc] = src[cc];
        dst[cc + 1] = src[cc + 1];
        return;
    }

    const int nl = lane & 15;
    const int ml = (lane >> 4) * 4;
    const int col = s * 64 + w * 16 + nl;  // this lane's h column

    // hoisted staging base pointers (constant across K-loop)
    const int r = lane >> 3;
    const int c = (lane & 7) ^ r;
    const ushort* X = Xall + t * 512;
    const ushort* xb[2];
    const ushort* hbp[2];
#pragma unroll
    for (int u = 0; u < 2; ++u) {
        const int srow = m0 + (w * 2 + u) * 8 + r;
        const int orig = perm[srow];
        xb[u] = X + (size_t)orig * 4096 + c * 8;
        hbp[u] = Hin + (size_t)srow * 512 + c * 8;
    }
    const ushort* wi[6];
    const ushort* wh[6];
#pragma unroll
    for (int j = 0; j < 6; ++j) {
        const int u = w * 6 + j;
        const int grow = (u >> 3) * 512 + s * 64 + (u & 7) * 8 + r;
        wi[j] = Wih + (size_t)grow * 512 + c * 8;
        wh[j] = Whh + (size_t)grow * 512 + c * 8;
    }

    // acc init with biases (depends only on column)
    floatx4 accr[4], accz[4], accn[4], acch[4];
    {
        const float br_ = bih[col] + bhh[col];
        const float bz_ = bih[512 + col] + bhh[512 + col];
        const float bn_i = bih[1024 + col];
        const float bn_h = bhh[1024 + col];
        const floatx4 vr = {br_, br_, br_, br_};
        const floatx4 vz = {bz_, bz_, bz_, bz_};
        const floatx4 vi = {bn_i, bn_i, bn_i, bn_i};
        const floatx4 vh = {bn_h, bn_h, bn_h, bn_h};
#pragma unroll
        for (int i = 0; i < 4; ++i) { accr[i] = vr; accz[i] = vz; accn[i] = vi; acch[i] = vh; }
    }

    for (int k0 = 0; k0 < 512; k0 += 64) {
#pragma unroll
        for (int u = 0; u < 2; ++u) {
            const int ua = w * 2 + u;
            load_lds16(xb[u] + k0, &sX[ua * 512]);
            load_lds16(hbp[u] + k0, &sH[ua * 512]);
        }
#pragma unroll
        for (int j = 0; j < 6; ++j) {
            const int u = w * 6 + j;
            load_lds16(wi[j] + k0, &sBih[u * 512]);
            load_lds16(wh[j] + k0, &sBhh[u * 512]);
        }
        __syncthreads();
#pragma unroll
        for (int kk = 0; kk < 2; ++kk) {
            const int cb = kk * 32 + (lane >> 4) * 8;
            short8 ax[4], ah[4];
#pragma unroll
            for (int i = 0; i < 4; ++i) {
                ax[i] = lds_read8(sX, i * 16 + nl, cb);
                ah[i] = lds_read8(sH, i * 16 + nl, cb);
            }
            const short8 bir = lds_read8(sBih, w * 16 + nl, cb);
            const short8 biz = lds_read8(sBih, 64 + w * 16 + nl, cb);
            const short8 bin = lds_read8(sBih, 128 + w * 16 + nl, cb);
            const short8 bhr = lds_read8(sBhh, w * 16 + nl, cb);
            const short8 bhz = lds_read8(sBhh, 64 + w * 16 + nl, cb);
            const short8 bhn = lds_read8(sBhh, 128 + w * 16 + nl, cb);
#pragma unroll
            for (int i = 0; i < 4; ++i) {
                accr[i] = __builtin_amdgcn_mfma_f32_16x16x32_bf16(ax[i], bir, accr[i], 0, 0, 0);
                accr[i] = __builtin_amdgcn_mfma_f32_16x16x32_bf16(ah[i], bhr, accr[i], 0, 0, 0);
                accz[i] = __builtin_amdgcn_mfma_f32_16x16x32_bf16(ax[i], biz, accz[i], 0, 0, 0);
                accz[i] = __builtin_amdgcn_mfma_f32_16x16x32_bf16(ah[i], bhz, accz[i], 0, 0, 0);
                accn[i] = __builtin_amdgcn_mfma_f32_16x16x32_bf16(ax[i], bin, accn[i], 0, 0, 0);
                acch[i] = __builtin_amdgcn_mfma_f32_16x16x32_bf16(ah[i], bhn, acch[i], 0, 0, 0);
            }
        }
        __syncthreads();
    }

    // epilogue: gates + positional mask (sorted rows)
    const bool full = (m0 + 64 <= na);
#pragma unroll
    for (int i = 0; i < 4; ++i) {
#pragma unroll
        for (int r4 = 0; r4 < 4; ++r4) {
            const int lr = i * 16 + ml + r4;
            const int row = m0 + lr;
            const float rg = fast_sigmoid(accr[i][r4]);
            const float zg = fast_sigmoid(accz[i][r4]);
            const float ng = fast_tanh(accn[i][r4] + rg * acch[i][r4]);
            const size_t off = (size_t)row * 512 + col;
            const float ho = hf[off];
            const bool act = full || (row < na);
            const float hv = act ? ((1.0f - zg) * ng + zg * ho) : ho;
            hf[off] = hv;
            Hout[off] = f2bf(hv);
        }
    }
}

// ---------- v_net: tanh(enc @ W_v^T + b_v), one wave per row (original space) ----------
__global__ __launch_bounds__(256) void v_kernel(const ushort* __restrict__ enc,
                                                const float* __restrict__ Wv,
                                                const float* __restrict__ bv,
                                                float* __restrict__ out) {
    const int row = blockIdx.x * 4 + (threadIdx.x >> 6);
    const int lane = threadIdx.x & 63;
    const ushort* e = enc + (size_t)row * 1024;
    float s = 0.0f;
#pragma unroll
    for (int i = 0; i < 16; ++i) {
        int k = lane + i * 64;
        s += bf2f(e[k]) * Wv[k];
    }
#pragma unroll
    for (int off = 32; off; off >>= 1) s += __shfl_down(s, off, 64);
    if (lane == 0) out[row] = fast_tanh(s + bv[0]);
}

// ---------- to_probs: softmax(relu(h @ W_pr^T + b_pr)); h in sorted space ----------
__global__ __launch_bounds__(256) void probs_kernel(const float* __restrict__ h,
                                                    const float* __restrict__ Wpr,
                                                    const float* __restrict__ bpr,
                                                    const int* __restrict__ perm,
                                                    float* __restrict__ out) {
    const int srow = blockIdx.x * 4 + (threadIdx.x >> 6);
    const int lane = threadIdx.x & 63;
    const float* hr = h + (size_t)srow * 512;
    float p0 = 0.f, p1 = 0.f, p2 = 0.f;
#pragma unroll
    for (int i = 0; i < 8; ++i) {
        int k = lane + i * 64;
        float x = hr[k];
        p0 += x * Wpr[k];
        p1 += x * Wpr[512 + k];
        p2 += x * Wpr[1024 + k];
    }
#pragma unroll
    for (int off = 32; off; off >>= 1) {
        p0 += __shfl_down(p0, off, 64);
        p1 += __shfl_down(p1, off, 64);
        p2 += __shfl_down(p2, off, 64);
    }
    if (lane == 0) {
        const int orow = perm[srow];
        p0 = fmaxf(p0 + bpr[0], 0.f);
        p1 = fmaxf(p1 + bpr[1], 0.f);
        p2 = fmaxf(p2 + bpr[2], 0.f);
        float m = fmaxf(p0, fmaxf(p1, p2));
        float e0 = __expf(p0 - m), e1 = __expf(p1 - m), e2 = __expf(p2 - m);
        float inv = 1.0f / (e0 + e1 + e2);
        out[orow * 3 + 0] = e0 * inv;
        out[orow * 3 + 1] = e1 * inv;
        out[orow * 3 + 2] = e2 * inv;
    }
}

extern "C" void kernel_launch(void* const* d_in, const int* in_sizes, int n_in,
                              void* d_out, int out_size, void* d_ws, size_t ws_size,
                              hipStream_t stream) {
    const float* obs   = (const float*)d_in[0];   // [4096,4096]
    const float* nbr   = (const float*)d_in[1];   // [4096,8,512]
    const int*   cnt   = (const int*)d_in[2];     // [4096]
    const float* W_ds  = (const float*)d_in[3];   // [1024,4096]
    const float* b_ds  = (const float*)d_in[4];
    const float* W_pol = (const float*)d_in[5];   // [512,1024]
    const float* b_pol = (const float*)d_in[6];
    const float* W_v   = (const float*)d_in[7];   // [1,1024]
    const float* b_v   = (const float*)d_in[8];
    const float* W_ih  = (const float*)d_in[9];   // [1536,512]
    const float* b_ih  = (const float*)d_in[10];
    const float* W_hh  = (const float*)d_in[11];  // [1536,512]
    const float* b_hh  = (const float*)d_in[12];
    const float* W_pr  = (const float*)d_in[13];  // [3,512]
    const float* b_pr  = (const float*)d_in[14];
    float* out = (float*)d_out;  // [4096*3 probs][4096 state_vals]

    // workspace layout
    ushort* obs_b  = (ushort*)d_ws;              // 16777216 (32 MB)
    ushort* Wds_b  = obs_b + 16777216;           // 4194304  (8 MB)
    ushort* Wpol_b = Wds_b + 4194304;            // 524288   (1 MB)
    ushort* Wih_b  = Wpol_b + 524288;            // 786432   (1.5 MB)
    ushort* Whh_b  = Wih_b + 786432;             // 786432   (1.5 MB)
    ushort* enc_b  = Whh_b + 786432;             // 4194304  (8 MB)
    ushort* h_b0   = enc_b + 4194304;            // 2097152  (4 MB)
    ushort* h_b1   = h_b0 + 2097152;             // 2097152  (4 MB)
    float*  h_f    = (float*)(h_b1 + 2097152);   // 2097152 floats (8 MB)
    float*  part   = h_f + 2097152;              // 8388608 floats (32 MB), reused as nbr_b
    ushort* nbr_b  = (ushort*)part;              // 16777216 ushorts (32 MB) AFTER combine
    int*    perm   = (int*)(part + 8388608);     // 4096
    int*    inv    = perm + 4096;                // 4096
    int*    nact   = inv + 4096;                 // 16
    // total ~100 MB + 32 KB

    // 0) sort rows by neighbor count (descending)
    sort_by_cnt<<<1, 256, 0, stream>>>(cnt, perm, inv, nact);

    // 1) convert obs + weights to bf16 (nbr converted later into the split-K scratch)
    cvt_f32_bf16<<<16384, 256, 0, stream>>>(obs, obs_b, 4194304);
    cvt_f32_bf16<<<4096, 256, 0, stream>>>(W_ds, Wds_b, 1048576);
    cvt_f32_bf16<<<512, 256, 0, stream>>>(W_pol, Wpol_b, 131072);
    cvt_f32_bf16<<<768, 256, 0, stream>>>(W_ih, Wih_b, 196608);
    cvt_f32_bf16<<<768, 256, 0, stream>>>(W_hh, Whh_b, 196608);

    // 2) enc = relu(obs @ W_ds^T + b_ds), BN=128 split-K=2 -> 1024 blocks (~4/CU)
    gemm64<3, 128, 2, false><<<dim3(8, 64, 2), 256, 0, stream>>>(
        obs_b, 4096, Wds_b, 4096, nullptr, nullptr, nullptr, part, 1024, 4096, 4194304);
    combine_relu<<<4096, 256, 0, stream>>>(part, part + 4194304, b_ds, enc_b, 1048576);

    // 3) nbr -> bf16 into the (now free) split-K scratch
    cvt_f32_bf16<<<16384, 256, 0, stream>>>(nbr, nbr_b, 4194304);

    // 4) pol = relu(enc @ W_pol^T + b_pol) scattered into sorted space (h_b0 + h_f)
    gemm64<2, 64, 1, true><<<dim3(8, 64, 1), 256, 0, stream>>>(
        enc_b, 1024, Wpol_b, 1024, b_pol, inv, h_b0, h_f, 512, 1024, 0);

    // 5) state_vals (original space)
    v_kernel<<<1024, 256, 0, stream>>>(enc_b, W_v, b_v, out + 12288);

    // 6) GRU: 8 fused steps in sorted space, h bf16 ping-pong, hf in-place master
    for (int t = 0; t < 8; ++t) {
        const ushort* hin = (t & 1) ? h_b1 : h_b0;
        ushort* hout = (t & 1) ? h_b0 : h_b1;
        gru_step<<<dim3(8, 64), 256, 0, stream>>>(nbr_b, hin, Wih_b, Whh_b,
                                                  b_ih, b_hh, perm, nact, h_f, hout, t);
    }

    // 7) probs (sorted -> original scatter)
    probs_kernel<<<1024, 256, 0, stream>>>(h_f, W_pr, b_pr, perm, out);
}